// Round 1
// baseline (54.636 us; speedup 1.0000x reference)
//
#include <hip/hip_runtime.h>

// Problem dims (fixed by reference): B=8, L=12, T=1024, H=256
#define RWS 96      // B*L rows
#define TT  1024    // timesteps
#define HH  256     // features
#define CT  64      // chunk of timesteps per block
#define NC  (TT/CT) // 16 chunks per row

// ---------------------------------------------------------------------------
// K1: per chunk (row,c): compute e[t]=exp(h[t]·w + b) and chunk partial
// weighted sums W[row][c][f] = sum_{t in chunk} e[t]*h[t][f].
// Reads h exactly once. Wave-per-timestep dot; per-lane float4 weighted acc,
// combined across the 4 waves via LDS.
// ---------------------------------------------------------------------------
__global__ __launch_bounds__(256) void k1_scores(
    const float* __restrict__ h, const float* __restrict__ attn_w,
    const float* __restrict__ attn_b, float* __restrict__ e_g,
    float* __restrict__ W_g) {
  const int blk  = blockIdx.x;
  const int row  = blk / NC;
  const int c    = blk % NC;
  const int t0   = c * CT;
  const int tid  = threadIdx.x;
  const int lane = tid & 63;
  const int wave = tid >> 6;

  const float4 wv  = reinterpret_cast<const float4*>(attn_w)[lane];
  const float bias = attn_b[0];
  const float* hrow = h + (size_t)row * TT * HH;

  float4 acc = make_float4(0.f, 0.f, 0.f, 0.f);

  for (int tt = wave; tt < CT; tt += 4) {
    const int t = t0 + tt;
    const float4 hv =
        reinterpret_cast<const float4*>(hrow + (size_t)t * HH)[lane];
    float p = hv.x * wv.x + hv.y * wv.y + hv.z * wv.z + hv.w * wv.w;
#pragma unroll
    for (int off = 32; off; off >>= 1) p += __shfl_xor(p, off);
    const float e = __expf(p + bias);
    if (lane == 0) e_g[(size_t)row * TT + t] = e;
    acc.x = fmaf(e, hv.x, acc.x);
    acc.y = fmaf(e, hv.y, acc.y);
    acc.z = fmaf(e, hv.z, acc.z);
    acc.w = fmaf(e, hv.w, acc.w);
  }

  __shared__ float wlds[4][HH];
  reinterpret_cast<float4*>(wlds[wave])[lane] = acc;
  __syncthreads();
  const float wsum = wlds[0][tid] + wlds[1][tid] + wlds[2][tid] + wlds[3][tid];
  W_g[((size_t)row * NC + c) * HH + tid] = wsum;
}

// ---------------------------------------------------------------------------
// K2: per row: (a) inclusive scan of e over T -> invcum[t]=1/(cum+1e-12);
//              (b) exclusive prefix of W over chunks (in place).
// 256 threads: each owns 4 consecutive t for the scan; thread f handles
// feature f for the W prefix.
// ---------------------------------------------------------------------------
__global__ __launch_bounds__(256) void k2_scan(
    const float* __restrict__ e_g, float* __restrict__ invcum,
    float* __restrict__ W_g) {
  const int row  = blockIdx.x;
  const int tid  = threadIdx.x;
  const int lane = tid & 63;
  const int wave = tid >> 6;

  const float4 v = reinterpret_cast<const float4*>(e_g + (size_t)row * TT)[tid];
  const float s = v.x + v.y + v.z + v.w;
  float sc = s;
#pragma unroll
  for (int off = 1; off < 64; off <<= 1) {
    const float n = __shfl_up(sc, off);
    if (lane >= off) sc += n;
  }
  __shared__ float wsum[4];
  if (lane == 63) wsum[wave] = sc;
  __syncthreads();
  float woff = 0.f;
#pragma unroll
  for (int w = 0; w < 4; ++w)
    if (w < wave) woff += wsum[w];
  const float excl = woff + sc - s;
  const float c0 = excl + v.x;
  const float c1 = c0 + v.y;
  const float c2 = c1 + v.z;
  const float c3 = c2 + v.w;
  float4 ic;
  ic.x = 1.f / (c0 + 1e-12f);
  ic.y = 1.f / (c1 + 1e-12f);
  ic.z = 1.f / (c2 + 1e-12f);
  ic.w = 1.f / (c3 + 1e-12f);
  reinterpret_cast<float4*>(invcum + (size_t)row * TT)[tid] = ic;

  // exclusive prefix of chunk partial sums (feature = tid)
  float run = 0.f;
  float* Wr = W_g + (size_t)row * NC * HH + tid;
#pragma unroll
  for (int cc = 0; cc < NC; ++cc) {
    const float t = Wr[(size_t)cc * HH];
    Wr[(size_t)cc * HH] = run;
    run += t;
  }
}

// ---------------------------------------------------------------------------
// K3: per chunk (row,c): thread f scans t in chunk, seeded with the chunk's
// exclusive prefix; out = h + run * invcum. Coalesced 1KB loads/stores.
// ---------------------------------------------------------------------------
__global__ __launch_bounds__(256) void k3_out(
    const float* __restrict__ h, const float* __restrict__ e_g,
    const float* __restrict__ invcum, const float* __restrict__ W_g,
    float* __restrict__ out) {
  const int blk = blockIdx.x;
  const int row = blk / NC;
  const int c   = blk % NC;
  const int t0  = c * CT;
  const int tid = threadIdx.x;

  __shared__ float e_lds[CT];
  __shared__ float ic_lds[CT];
  if (tid < CT) {
    e_lds[tid] = e_g[(size_t)row * TT + t0 + tid];
  } else if (tid < 2 * CT) {
    ic_lds[tid - CT] = invcum[(size_t)row * TT + t0 + (tid - CT)];
  }
  __syncthreads();

  float run = W_g[((size_t)row * NC + c) * HH + tid];
  const float* hp = h + ((size_t)row * TT + t0) * HH + tid;
  float* op = out + ((size_t)row * TT + t0) * HH + tid;
#pragma unroll 4
  for (int tt = 0; tt < CT; ++tt) {
    const float hv = hp[(size_t)tt * HH];
    run = fmaf(e_lds[tt], hv, run);
    op[(size_t)tt * HH] = fmaf(run, ic_lds[tt], hv);
  }
}

extern "C" void kernel_launch(void* const* d_in, const int* in_sizes, int n_in,
                              void* d_out, int out_size, void* d_ws,
                              size_t ws_size, hipStream_t stream) {
  const float* h      = (const float*)d_in[0];
  const float* attn_w = (const float*)d_in[1];
  const float* attn_b = (const float*)d_in[2];
  float* out = (float*)d_out;

  // workspace layout (floats): e[R*T], invcum[R*T], W[R*NC*H]  (~2.4 MB)
  float* e_g    = (float*)d_ws;
  float* invcum = e_g + (size_t)RWS * TT;
  float* W_g    = invcum + (size_t)RWS * TT;

  k1_scores<<<RWS * NC, 256, 0, stream>>>(h, attn_w, attn_b, e_g, W_g);
  k2_scan<<<RWS, 256, 0, stream>>>(e_g, invcum, W_g);
  k3_out<<<RWS * NC, 256, 0, stream>>>(h, e_g, invcum, W_g, out);
}

// Round 2
// 54.397 us; speedup vs baseline: 1.0044x; 1.0044x over previous
//
#include <hip/hip_runtime.h>

// Problem dims (fixed by reference): B=8, L=12, T=1024, H=256
#define RWS 96      // B*L rows
#define TT  1024    // timesteps
#define HH  256     // features
#define CT  64      // chunk of timesteps per K1 block / K3 wave
#define NC  (TT/CT) // 16 chunks per row

// ---------------------------------------------------------------------------
// K1: per chunk (row,c): e[t]=exp(h[t]·w + b) and chunk partial weighted sums
// W[row][c][f] = sum_{t in chunk} e[t]*h[t][f]. Reads h exactly once.
// Wave-per-timestep dot (float4/lane + shfl reduce); per-lane weighted acc,
// combined across the 4 waves via LDS.
// ---------------------------------------------------------------------------
__global__ __launch_bounds__(256) void k1_scores(
    const float* __restrict__ h, const float* __restrict__ attn_w,
    const float* __restrict__ attn_b, float* __restrict__ e_g,
    float* __restrict__ W_g) {
  const int blk  = blockIdx.x;
  const int row  = blk / NC;
  const int c    = blk % NC;
  const int t0   = c * CT;
  const int tid  = threadIdx.x;
  const int lane = tid & 63;
  const int wave = tid >> 6;

  const float4 wv  = reinterpret_cast<const float4*>(attn_w)[lane];
  const float bias = attn_b[0];
  const float* hrow = h + (size_t)row * TT * HH;

  float4 acc = make_float4(0.f, 0.f, 0.f, 0.f);

  for (int tt = wave; tt < CT; tt += 4) {
    const int t = t0 + tt;
    const float4 hv =
        reinterpret_cast<const float4*>(hrow + (size_t)t * HH)[lane];
    float p = hv.x * wv.x + hv.y * wv.y + hv.z * wv.z + hv.w * wv.w;
#pragma unroll
    for (int off = 32; off; off >>= 1) p += __shfl_xor(p, off);
    const float e = __expf(p + bias);
    if (lane == 0) e_g[(size_t)row * TT + t] = e;
    acc.x = fmaf(e, hv.x, acc.x);
    acc.y = fmaf(e, hv.y, acc.y);
    acc.z = fmaf(e, hv.z, acc.z);
    acc.w = fmaf(e, hv.w, acc.w);
  }

  __shared__ float wlds[4][HH];
  reinterpret_cast<float4*>(wlds[wave])[lane] = acc;
  __syncthreads();
  const float wsum = wlds[0][tid] + wlds[1][tid] + wlds[2][tid] + wlds[3][tid];
  W_g[((size_t)row * NC + c) * HH + tid] = wsum;
}

// ---------------------------------------------------------------------------
// K3: per block: one quarter-row (256 timesteps). Wave w owns chunk of 64
// timesteps; lane owns 4 contiguous features (float4). The e-prefix (scalar)
// and W-chunk-prefix (float4, <=15 coalesced L2-hit loads) are computed
// redundantly per wave — no separate scan kernel, no serial dependency chain.
// out = h + run*(1/(cum_e+1e-12)), float4 loads/stores (1 KB/instr/wave).
// ---------------------------------------------------------------------------
__global__ __launch_bounds__(256) void k3_out(
    const float* __restrict__ h, const float* __restrict__ e_g,
    const float* __restrict__ W_g, float* __restrict__ out) {
  const int blk  = blockIdx.x;
  const int row  = blk >> 2;         // 4 blocks per row
  const int q    = blk & 3;          // quarter index
  const int tid  = threadIdx.x;
  const int lane = tid & 63;
  const int wave = tid >> 6;

  // stage full e row (4 KB) in LDS
  __shared__ float e_lds[TT];
  reinterpret_cast<float4*>(e_lds)[tid] =
      reinterpret_cast<const float4*>(e_g + (size_t)row * TT)[tid];
  __syncthreads();

  const int ts = q * 256 + wave * CT;   // this wave's chunk start

  // exclusive scalar prefix: sum e[0:ts)
  float ex = 0.f;
  for (int i = lane; i < ts; i += 64) ex += e_lds[i];
#pragma unroll
  for (int off = 32; off; off >>= 1) ex += __shfl_xor(ex, off);

  // exclusive W prefix over chunks before ts (lane's 4 features)
  float4 run = make_float4(0.f, 0.f, 0.f, 0.f);
  const int ncc = ts / CT;
  const float4* Wp = reinterpret_cast<const float4*>(W_g + (size_t)row * NC * HH) + lane;
  for (int cc = 0; cc < ncc; ++cc) {
    const float4 wv = Wp[(size_t)cc * (HH / 4)];
    run.x += wv.x; run.y += wv.y; run.z += wv.z; run.w += wv.w;
  }

  // sequential scan over the wave's 64 timesteps
  const float4* hp =
      reinterpret_cast<const float4*>(h + ((size_t)row * TT + ts) * HH) + lane;
  float4* op =
      reinterpret_cast<float4*>(out + ((size_t)row * TT + ts) * HH) + lane;
  float cum = ex;
#pragma unroll 4
  for (int tt = 0; tt < CT; ++tt) {
    const float e = e_lds[ts + tt];          // LDS broadcast
    cum += e;
    const float ic = 1.f / (cum + 1e-12f);
    const float4 hv = hp[(size_t)tt * (HH / 4)];
    run.x = fmaf(e, hv.x, run.x);
    run.y = fmaf(e, hv.y, run.y);
    run.z = fmaf(e, hv.z, run.z);
    run.w = fmaf(e, hv.w, run.w);
    float4 o;
    o.x = fmaf(run.x, ic, hv.x);
    o.y = fmaf(run.y, ic, hv.y);
    o.z = fmaf(run.z, ic, hv.z);
    o.w = fmaf(run.w, ic, hv.w);
    op[(size_t)tt * (HH / 4)] = o;
  }
}

extern "C" void kernel_launch(void* const* d_in, const int* in_sizes, int n_in,
                              void* d_out, int out_size, void* d_ws,
                              size_t ws_size, hipStream_t stream) {
  const float* h      = (const float*)d_in[0];
  const float* attn_w = (const float*)d_in[1];
  const float* attn_b = (const float*)d_in[2];
  float* out = (float*)d_out;

  // workspace layout (floats): e[R*T], W[R*NC*H]  (~1.9 MB)
  float* e_g = (float*)d_ws;
  float* W_g = e_g + (size_t)RWS * TT;

  k1_scores<<<RWS * NC, 256, 0, stream>>>(h, attn_w, attn_b, e_g, W_g);
  k3_out<<<RWS * 4, 256, 0, stream>>>(h, e_g, W_g, out);
}